// Round 5
// baseline (50.087 us; speedup 1.0000x reference)
//
#include <hip/hip_runtime.h>
#include <hip/hip_bf16.h>

// Problem constants (reference: K=512, D=128, N=8192)
#define KC 512
#define DD 128
#define NP 8192

// ws layout: [0, 2KB): sumc2 (512 f32); [4KB, 4KB+256KB): CkT (128 x 512 f32)

// Prep kernel (98 blocks x 256):
//   blocks 0..63  : transpose Ck (512x128) -> CkT (128x512); coalesced float4 reads
//   block  64     : sumc2[k] = sum_d Ck[k][d]^2
//   blocks 65..97 : zero d_out (66048 floats)
__global__ __launch_bounds__(256) void kprep(const float* __restrict__ Ck,
                                             float* __restrict__ CkT,
                                             float* __restrict__ sumc2,
                                             float* __restrict__ out) {
    const int b = blockIdx.x;
    const int t = threadIdx.x;
    if (b < 64) {
        const float4 v = *(const float4*)(Ck + b * 1024 + t * 4);
        const int k = b * 8 + (t >> 5);
        const int d = (t & 31) * 4;
        CkT[(d + 0) * KC + k] = v.x;
        CkT[(d + 1) * KC + k] = v.y;
        CkT[(d + 2) * KC + k] = v.z;
        CkT[(d + 3) * KC + k] = v.w;
    } else if (b == 64) {
        #pragma unroll
        for (int c = 0; c < 2; ++c) {
            const int k = t + c * 256;
            const float4* row = (const float4*)(Ck + k * DD);
            float s = 0.f;
            #pragma unroll
            for (int i = 0; i < 32; ++i) {
                const float4 v = row[i];
                s += v.x * v.x + v.y * v.y + v.z * v.z + v.w * v.w;
            }
            sumc2[k] = s;
        }
    } else {
        const int base = (b - 65) * 2048 + t;
        #pragma unroll
        for (int i = 0; i < 8; ++i) {
            const int idx = base + i * 256;
            if (idx < KC * DD + KC) out[idx] = 0.f;
        }
    }
}

// Main kernel: 512 blocks x 256 threads (4 waves) = 2 blocks/CU, 8 waves/CU.
// Block: 16 points. Wave w owns centroid quarter [128w, 128w+128);
// lane owns 2 consecutive cents c0 = 128w + 2*lane -> coalesced dwordx2 loads
// (512B/wave-instr) straight from L2 (no LDS staging for c, no loop barriers).
// Centroid L2 traffic: 512 blocks * 256KB = 134 MB (~50% of L2 share) -- was
// 268 MB (~100%) in round 4; that saturation was the latency blow-up.
// x: staged once in LDS (8 KB), read as wave-uniform float4 broadcasts.
// acc: 16 points x 2 cents = 32 VGPRs; depth-2 ping-pong c prefetch (static idx).
// Accumulation: single fmaf chain d=0..127 ascending (round-4 ordering, absmax 4e-3).
__global__ __launch_bounds__(256) void kmain(const float* __restrict__ X,
                                             const float* __restrict__ CkT,
                                             const float* __restrict__ sumc2,
                                             float* __restrict__ out) {
    __shared__ __align__(16) float xs[16 * DD];   // 8 KB
    __shared__ float bvw[4][16];
    __shared__ int   biw[4][16];
    __shared__ int   win[16];

    const int tid  = threadIdx.x;
    const int lane = tid & 63;
    const int w    = tid >> 6;
    const int p0   = blockIdx.x * 16;
    const int c0   = w * 128 + 2 * lane;

    // stage x tile (16 x 128 = 512 float4; 2 per thread, coalesced)
    {
        const float4* Xv = (const float4*)(X + p0 * DD);
        float4* xv = (float4*)xs;
        xv[tid]       = Xv[tid];
        xv[tid + 256] = Xv[tid + 256];
    }
    __syncthreads();

    const float* cp = CkT + c0;

    // depth-2 ping-pong prefetch buffers (all indices compile-time constant)
    float2 cb[2][4];
    #pragma unroll
    for (int dd = 0; dd < 4; ++dd) cb[0][dd] = *(const float2*)(cp + (0 + dd) * KC);
    #pragma unroll
    for (int dd = 0; dd < 4; ++dd) cb[1][dd] = *(const float2*)(cp + (4 + dd) * KC);

    float acc[16][2];
    #pragma unroll
    for (int p = 0; p < 16; ++p) { acc[p][0] = 0.f; acc[p][1] = 0.f; }

    #pragma unroll 2
    for (int t = 0; t < 32; ++t) {
        const int b = t & 1;
        float2 cc[4];
        #pragma unroll
        for (int dd = 0; dd < 4; ++dd) cc[dd] = cb[b][dd];
        if (t < 30) {
            #pragma unroll
            for (int dd = 0; dd < 4; ++dd)
                cb[b][dd] = *(const float2*)(cp + ((t + 2) * 4 + dd) * KC);
        }
        // two chunks of 8 points to limit live xf registers
        #pragma unroll
        for (int half = 0; half < 2; ++half) {
            float4 xf[8];
            #pragma unroll
            for (int i = 0; i < 8; ++i)
                xf[i] = *(const float4*)&xs[(half * 8 + i) * DD + t * 4];  // uniform -> broadcast
            #pragma unroll
            for (int dd = 0; dd < 4; ++dd) {
                #pragma unroll
                for (int i = 0; i < 8; ++i) {
                    const int p = half * 8 + i;
                    const float xv = (&xf[i].x)[dd];
                    acc[p][0] = fmaf(xv, cc[dd].x, acc[p][0]);
                    acc[p][1] = fmaf(xv, cc[dd].y, acc[p][1]);
                }
            }
        }
    }

    // per-thread argmin over its 2 centroids (ascending index, strict <)
    float bestv[16];
    int   besti[16];
    #pragma unroll
    for (int p = 0; p < 16; ++p) { bestv[p] = 3.4e38f; besti[p] = 0; }
    const float2 s2 = *(const float2*)(sumc2 + c0);
    #pragma unroll
    for (int j = 0; j < 2; ++j) {
        const float s2j = (&s2.x)[j];
        #pragma unroll
        for (int p = 0; p < 16; ++p) {
            const float v = fmaf(-2.f, acc[p][j], s2j);   // monotonic proxy for d2
            if (v < bestv[p]) { bestv[p] = v; besti[p] = c0 + j; }
        }
    }
    // wave butterfly, tie-break on smaller index (jnp.argmin = first min)
    #pragma unroll
    for (int off = 1; off < 64; off <<= 1) {
        #pragma unroll
        for (int p = 0; p < 16; ++p) {
            const float ov = __shfl_xor(bestv[p], off);
            const int   oi = __shfl_xor(besti[p], off);
            if (ov < bestv[p] || (ov == bestv[p] && oi < besti[p])) {
                bestv[p] = ov; besti[p] = oi;
            }
        }
    }
    if (lane == 0) {
        #pragma unroll
        for (int p = 0; p < 16; ++p) { bvw[w][p] = bestv[p]; biw[w][p] = besti[p]; }
    }
    __syncthreads();
    if (tid < 16) {
        float bv = bvw[0][tid];
        int   bi = biw[0][tid];
        #pragma unroll
        for (int w2 = 1; w2 < 4; ++w2) {
            const float v = bvw[w2][tid];
            const int   i2 = biw[w2][tid];
            if (v < bv) { bv = v; bi = i2; }   // ties keep lower w = lower index
        }
        win[tid] = bi;
    }
    __syncthreads();

    // fused scatter: 16 points x 128 dims (lanes hit distinct addresses)
    #pragma unroll
    for (int i = 0; i < 8; ++i) {
        const int flat = tid + 256 * i;     // p*128 + d
        const int p = flat >> 7;
        const int d = flat & 127;
        atomicAdd(&out[win[p] * DD + d], xs[flat]);
    }
    if (tid < 16) atomicAdd(&out[KC * DD + win[tid]], 1.0f);
}

extern "C" void kernel_launch(void* const* d_in, const int* in_sizes, int n_in,
                              void* d_out, int out_size, void* d_ws, size_t ws_size,
                              hipStream_t stream) {
    const float* locF = (const float*)d_in[0];
    const float* Ck   = (const float*)d_in[1];
    float* out   = (float*)d_out;
    float* sumc2 = (float*)d_ws;
    float* CkT   = (float*)((char*)d_ws + 4096);

    hipLaunchKernelGGL(kprep, dim3(98), dim3(256), 0, stream, Ck, CkT, sumc2, out);
    hipLaunchKernelGGL(kmain, dim3(512), dim3(256), 0, stream, locF, CkT, sumc2, out);
}